// Round 9
// baseline (573.760 us; speedup 1.0000x reference)
//
#include <hip/hip_runtime.h>
#include <stdint.h>

#define NN 50000   // N_NODES (fixed in reference)
#define NB 196     // ceil(NN/256) scan blocks

typedef unsigned short u16;
typedef _Float16 f16;
typedef __attribute__((ext_vector_type(8))) _Float16 half8;   // MFMA A/B fragment (4 VGPRs)
typedef __attribute__((ext_vector_type(4))) _Float16 half4;
typedef __attribute__((ext_vector_type(4))) float f32x4;

__device__ __forceinline__ float lrelu(float e){ return e > 0.f ? e : 0.2f * e; }

// ---------------- CSR build (dst-sorted adjacency incl. self-loops) ----------------

__global__ void count_k(const int* __restrict__ dst, int* __restrict__ cnt, int E){
  int i = blockIdx.x * 256 + threadIdx.x;
  int tot = E + NN;
  if (i >= tot) return;
  int d = (i < E) ? dst[i] : (i - E);        // self-loop edges appended
  atomicAdd(&cnt[d], 1);
}

__global__ __launch_bounds__(256) void scan_part_k(const int* __restrict__ cnt,
                                                   int* __restrict__ bsum){
  __shared__ int lds[256];
  int tid = threadIdx.x;
  int idx = blockIdx.x * 256 + tid;
  lds[tid] = (idx < NN) ? cnt[idx] : 0;
  __syncthreads();
#pragma unroll
  for (int off = 128; off >= 1; off >>= 1){
    if (tid < off) lds[tid] += lds[tid + off];
    __syncthreads();
  }
  if (tid == 0) bsum[blockIdx.x] = lds[0];
}

__global__ __launch_bounds__(256) void scan_top_k(const int* __restrict__ bsum,
                                                  int* __restrict__ boff,
                                                  int* __restrict__ row_ptr){
  __shared__ int lds[256];
  int tid = threadIdx.x;
  int v = (tid < NB) ? bsum[tid] : 0;
  lds[tid] = v;
  __syncthreads();
#pragma unroll
  for (int off = 1; off < 256; off <<= 1){
    int t = (tid >= off) ? lds[tid - off] : 0;
    __syncthreads();
    lds[tid] += t;
    __syncthreads();
  }
  if (tid < NB) boff[tid] = lds[tid] - v;    // exclusive
  if (tid == 255) row_ptr[NN] = lds[255];    // grand total
}

__global__ __launch_bounds__(256) void scan_fin_k(const int* __restrict__ cnt,
                                                  const int* __restrict__ boff,
                                                  int* __restrict__ row_ptr,
                                                  int* __restrict__ cursor){
  __shared__ int lds[256];
  int tid = threadIdx.x;
  int idx = blockIdx.x * 256 + tid;
  int v = (idx < NN) ? cnt[idx] : 0;
  lds[tid] = v;
  __syncthreads();
#pragma unroll
  for (int off = 1; off < 256; off <<= 1){
    int t = (tid >= off) ? lds[tid - off] : 0;
    __syncthreads();
    lds[tid] += t;
    __syncthreads();
  }
  if (idx < NN){
    int r = boff[blockIdx.x] + lds[tid] - v; // exclusive prefix
    row_ptr[idx] = r;
    cursor[idx]  = r;
  }
}

__global__ void scatter_k(const int* __restrict__ src, const int* __restrict__ dst,
                          int* __restrict__ cursor, int* __restrict__ csr, int E){
  int i = blockIdx.x * 256 + threadIdx.x;
  int tot = E + NN;
  if (i >= tot) return;
  int s, d;
  if (i < E){ s = src[i]; d = dst[i]; } else { s = i - E; d = i - E; }
  int pos = atomicAdd(&cursor[d], 1);
  csr[pos] = s;
}

// -------- W transpose+convert: fp32 [K,N] -> fp16 [N,K] -----------------------------

__global__ void transpose_k(const float* __restrict__ W, f16* __restrict__ Wt, int K, int N){
  int i = blockIdx.x * 256 + threadIdx.x;
  if (i >= K * N) return;
  int n = i / K, k = i - n * K;
  Wt[i] = (f16)W[k * N + n];                 // write coalesced
}

// ---- m97-style tiled GEMM: C[M,N](fp16) = A[M,K]*B[K,N], Bt fp16 [N,K] ------------
// 128x128 tile, 4 waves 2x2, fragment-major LDS (conflict-free), 8 ds_read_b128 +
// 16 MFMA per wave per K-step.

template<bool A_FP32>
__global__ __launch_bounds__(256) void gemm_tile_k(const void* __restrict__ Aptr,
                                                   const f16* __restrict__ Bt,
                                                   f16* __restrict__ C,
                                                   int M, int N, int K){
  __shared__ f16 As[128 * 32];
  __shared__ f16 Bs[128 * 32];
  const int tid  = threadIdx.x;
  const int wave = tid >> 6, lane = tid & 63;
  const int quad = lane >> 4, l16 = lane & 15;
  const int wm = wave >> 1, wn = wave & 1;
  const int m0 = blockIdx.x * 128, n0 = blockIdx.y * 128;
  const int srow = tid >> 2;
  const int sc   = tid & 3;

  f32x4 acc[4][4] = {};

  for (int k0 = 0; k0 < K; k0 += 32){
#pragma unroll
    for (int rep = 0; rep < 2; rep++){
      int row = rep * 64 + srow;
      int gm = m0 + row;
      half8 va = {0,0,0,0,0,0,0,0};
      if (gm < M){
        if (A_FP32){
          const float* A = (const float*)Aptr + (size_t)gm * K + k0 + sc * 8;
          const f32x4 f0 = *(const f32x4*)(A);
          const f32x4 f1 = *(const f32x4*)(A + 4);
          va[0] = (f16)f0.x; va[1] = (f16)f0.y; va[2] = (f16)f0.z; va[3] = (f16)f0.w;
          va[4] = (f16)f1.x; va[5] = (f16)f1.y; va[6] = (f16)f1.z; va[7] = (f16)f1.w;
        } else {
          va = *(const half8*)((const f16*)Aptr + (size_t)gm * K + k0 + sc * 8);
        }
      }
      *(half8*)(&As[(((row >> 4) * 64) + sc * 16 + (row & 15)) * 8]) = va;
    }
#pragma unroll
    for (int rep = 0; rep < 2; rep++){
      int row = rep * 64 + srow;
      half8 vb = *(const half8*)(Bt + (size_t)(n0 + row) * K + k0 + sc * 8);
      *(half8*)(&Bs[(((row >> 4) * 64) + sc * 16 + (row & 15)) * 8]) = vb;
    }

    __syncthreads();
    half8 af[4], bf[4];
#pragma unroll
    for (int i = 0; i < 4; i++)
      af[i] = *(const half8*)(&As[((wm * 4 + i) * 64 + lane) * 8]);
#pragma unroll
    for (int j = 0; j < 4; j++)
      bf[j] = *(const half8*)(&Bs[((wn * 4 + j) * 64 + lane) * 8]);
#pragma unroll
    for (int i = 0; i < 4; i++)
#pragma unroll
      for (int j = 0; j < 4; j++)
        acc[i][j] = __builtin_amdgcn_mfma_f32_16x16x32_f16(af[i], bf[j], acc[i][j], 0, 0, 0);
    __syncthreads();
  }

#pragma unroll
  for (int i = 0; i < 4; i++){
#pragma unroll
    for (int j = 0; j < 4; j++){
      int n = n0 + (wn * 4 + j) * 16 + l16;
#pragma unroll
      for (int r = 0; r < 4; r++){
        int mm = m0 + (wm * 4 + i) * 16 + quad * 4 + r;
        if (mm < M) C[(size_t)mm * N + n] = (f16)acc[i][j][r];
      }
    }
  }
}

// ---- narrow GEMM (layer 3): 64x64 tile --------------------------------------------

__global__ __launch_bounds__(256) void gemm_k(const f16* __restrict__ A,
                                              const f16* __restrict__ Bt,
                                              f16* __restrict__ C,
                                              int M, int N, int K){
  __shared__ f16 As[64 * 40];
  __shared__ f16 Bs[64 * 40];
  const int tid  = threadIdx.x;
  const int wave = tid >> 6, lane = tid & 63;
  const int quad = lane >> 4, l16 = lane & 15;
  const int m0 = blockIdx.x * 64, n0 = blockIdx.y * 64;
  const int srow = tid >> 2;
  const int scol = (tid & 3) * 8;

  f32x4 acc[4] = {};

  for (int k0 = 0; k0 < K; k0 += 32){
    half8 va = {0,0,0,0,0,0,0,0};
    int gm = m0 + srow;
    if (gm < M) va = *(const half8*)(A + (size_t)gm * K + k0 + scol);
    *(half8*)(&As[srow * 40 + scol]) = va;

    half8 vb = {0,0,0,0,0,0,0,0};
    int gn = n0 + srow;
    if (gn < N) vb = *(const half8*)(Bt + (size_t)gn * K + k0 + scol);
    *(half8*)(&Bs[srow * 40 + scol]) = vb;

    __syncthreads();
    half8 af = *(const half8*)(&As[(wave * 16 + l16) * 40 + quad * 8]);
#pragma unroll
    for (int i = 0; i < 4; i++){
      half8 bf = *(const half8*)(&Bs[(i * 16 + l16) * 40 + quad * 8]);
      acc[i] = __builtin_amdgcn_mfma_f32_16x16x32_f16(af, bf, acc[i], 0, 0, 0);
    }
    __syncthreads();
  }

#pragma unroll
  for (int i = 0; i < 4; i++){
    int n = n0 + i * 16 + l16;
#pragma unroll
    for (int r = 0; r < 4; r++){
      int m = m0 + wave * 16 + quad * 4 + r;
      if (m < M && n < N) C[(size_t)m * N + n] = (f16)acc[i][r];
    }
  }
}

// ---------------- attention coefficients (h fp16, att vectors fp32) ----------------

__global__ __launch_bounds__(256) void attn4_k(const f16* __restrict__ h,
                                               const float* __restrict__ atts,
                                               const float* __restrict__ attd,
                                               float* __restrict__ a_s,
                                               float* __restrict__ a_d){
  int w = blockIdx.x * 4 + (threadIdx.x >> 6);
  if (w >= NN) return;
  int lane = threadIdx.x & 63;
  const half4 hv = *(const half4*)(h + (size_t)w * 256 + lane * 4);
  const f32x4 sv = *(const f32x4*)(atts + lane * 4);
  const f32x4 dv = *(const f32x4*)(attd + lane * 4);
  float h0 = (float)hv.x, h1 = (float)hv.y, h2 = (float)hv.z, h3 = (float)hv.w;
  float ps = h0 * sv.x + h1 * sv.y + h2 * sv.z + h3 * sv.w;
  float pd = h0 * dv.x + h1 * dv.y + h2 * dv.z + h3 * dv.w;
#pragma unroll
  for (int off = 8; off >= 1; off >>= 1){
    ps += __shfl_xor(ps, off);
    pd += __shfl_xor(pd, off);
  }
  if ((lane & 15) == 0){
    a_s[w * 4 + (lane >> 4)] = ps;
    a_d[w * 4 + (lane >> 4)] = pd;
  }
}

__global__ __launch_bounds__(256) void attn1_k(const f16* __restrict__ h,
                                               const float* __restrict__ atts,
                                               const float* __restrict__ attd,
                                               float* __restrict__ a_s,
                                               float* __restrict__ a_d){
  int w = blockIdx.x * 4 + (threadIdx.x >> 6);
  if (w >= NN) return;
  int lane = threadIdx.x & 63;
  float ps = 0.f, pd = 0.f;
  if (lane < 40){
    float hv = (float)h[(size_t)w * 40 + lane];
    ps = hv * atts[lane];
    pd = hv * attd[lane];
  }
#pragma unroll
  for (int off = 32; off >= 1; off >>= 1){
    ps += __shfl_xor(ps, off);
    pd += __shfl_xor(pd, off);
  }
  if (lane == 0){ a_s[w] = ps; a_d[w] = pd; }
}

// ---- softmax factor precompute: 16 lanes per node, online (m,sum) + alpha store ----

// H=4: alpha[j*4+head] = exp(lrelu(a_s[s]+a_d[w]) - m_w) / denom_w
__global__ __launch_bounds__(256) void maxden4_k(const float* __restrict__ a_s,
                                                 const float* __restrict__ a_d,
                                                 const int* __restrict__ row_ptr,
                                                 const int* __restrict__ csr,
                                                 float* __restrict__ alpha){
  int w = blockIdx.x * 16 + (threadIdx.x >> 4);
  if (w >= NN) return;
  int gl = threadIdx.x & 15;
  int beg = row_ptr[w], end = row_ptr[w + 1];
  const f32x4 ad = *(const f32x4*)(a_d + (size_t)w * 4);

  float m0=-1e30f,m1=-1e30f,m2=-1e30f,m3=-1e30f;
  float s0=0.f,s1=0.f,s2=0.f,s3=0.f;
  for (int j = beg + gl; j < end; j += 16){
    int s = csr[j];
    const f32x4 as = *(const f32x4*)(a_s + (size_t)s * 4);
    float e, mn;
    e = lrelu(as.x + ad.x); mn = fmaxf(m0, e); s0 = s0*__expf(m0-mn) + __expf(e-mn); m0 = mn;
    e = lrelu(as.y + ad.y); mn = fmaxf(m1, e); s1 = s1*__expf(m1-mn) + __expf(e-mn); m1 = mn;
    e = lrelu(as.z + ad.z); mn = fmaxf(m2, e); s2 = s2*__expf(m2-mn) + __expf(e-mn); m2 = mn;
    e = lrelu(as.w + ad.w); mn = fmaxf(m3, e); s3 = s3*__expf(m3-mn) + __expf(e-mn); m3 = mn;
  }
#pragma unroll
  for (int k = 1; k < 16; k <<= 1){
    float mo, so, mn;
    mo=__shfl_xor(m0,k); so=__shfl_xor(s0,k); mn=fmaxf(m0,mo); s0=s0*__expf(m0-mn)+so*__expf(mo-mn); m0=mn;
    mo=__shfl_xor(m1,k); so=__shfl_xor(s1,k); mn=fmaxf(m1,mo); s1=s1*__expf(m1-mn)+so*__expf(mo-mn); m1=mn;
    mo=__shfl_xor(m2,k); so=__shfl_xor(s2,k); mn=fmaxf(m2,mo); s2=s2*__expf(m2-mn)+so*__expf(mo-mn); m2=mn;
    mo=__shfl_xor(m3,k); so=__shfl_xor(s3,k); mn=fmaxf(m3,mo); s3=s3*__expf(m3-mn)+so*__expf(mo-mn); m3=mn;
  }
  float i0 = 1.f/fmaxf(s0,1e-30f), i1 = 1.f/fmaxf(s1,1e-30f);
  float i2 = 1.f/fmaxf(s2,1e-30f), i3 = 1.f/fmaxf(s3,1e-30f);

  for (int j = beg + gl; j < end; j += 16){
    int s = csr[j];
    const f32x4 as = *(const f32x4*)(a_s + (size_t)s * 4);
    f32x4 al;
    al.x = __expf(lrelu(as.x + ad.x) - m0) * i0;
    al.y = __expf(lrelu(as.y + ad.y) - m1) * i1;
    al.z = __expf(lrelu(as.z + ad.z) - m2) * i2;
    al.w = __expf(lrelu(as.w + ad.w) - m3) * i3;
    *(f32x4*)(alpha + (size_t)j * 4) = al;
  }
}

// H=1
__global__ __launch_bounds__(256) void maxden1_k(const float* __restrict__ a_s,
                                                 const float* __restrict__ a_d,
                                                 const int* __restrict__ row_ptr,
                                                 const int* __restrict__ csr,
                                                 float* __restrict__ alpha){
  int w = blockIdx.x * 16 + (threadIdx.x >> 4);
  if (w >= NN) return;
  int gl = threadIdx.x & 15;
  int beg = row_ptr[w], end = row_ptr[w + 1];
  const float ad = a_d[w];

  float m = -1e30f, sum = 0.f;
  for (int j = beg + gl; j < end; j += 16){
    float e = lrelu(a_s[csr[j]] + ad);
    float mn = fmaxf(m, e);
    sum = sum*__expf(m-mn) + __expf(e-mn); m = mn;
  }
#pragma unroll
  for (int k = 1; k < 16; k <<= 1){
    float mo=__shfl_xor(m,k), so=__shfl_xor(sum,k);
    float mn=fmaxf(m,mo);
    sum = sum*__expf(m-mn) + so*__expf(mo-mn); m = mn;
  }
  float inv = 1.f/fmaxf(sum,1e-30f);
  for (int j = beg + gl; j < end; j += 16)
    alpha[j] = __expf(lrelu(a_s[csr[j]] + ad) - m) * inv;
}

// ---- aggregate: pure weighted gather (alpha precomputed) --------------------------

// H=4, C=64 -> out[N,256](fp16) = ELU(agg + bias)
__global__ __launch_bounds__(256) void agg4_k(const f16* __restrict__ h,
                                              const float* __restrict__ alpha,
                                              const int* __restrict__ row_ptr,
                                              const int* __restrict__ csr,
                                              const float* __restrict__ bias,
                                              f16* __restrict__ out){
  int w = blockIdx.x * 4 + (threadIdx.x >> 6);
  if (w >= NN) return;
  int lane = threadIdx.x & 63;
  int head = lane >> 4;
  int beg = row_ptr[w], end = row_ptr[w + 1];

  float acc0 = 0.f, acc1 = 0.f, acc2 = 0.f, acc3 = 0.f;
  int j = beg;
  for (; j + 4 <= end; j += 4){
    int s0 = csr[j], s1 = csr[j+1], s2 = csr[j+2], s3 = csr[j+3];
    float a0 = alpha[(size_t)j*4 + head];
    float a1 = alpha[(size_t)(j+1)*4 + head];
    float a2 = alpha[(size_t)(j+2)*4 + head];
    float a3 = alpha[(size_t)(j+3)*4 + head];
    half4 v0 = *(const half4*)(h + (size_t)s0*256 + lane*4);
    half4 v1 = *(const half4*)(h + (size_t)s1*256 + lane*4);
    half4 v2 = *(const half4*)(h + (size_t)s2*256 + lane*4);
    half4 v3 = *(const half4*)(h + (size_t)s3*256 + lane*4);
    acc0 += a0*(float)v0.x + a1*(float)v1.x + a2*(float)v2.x + a3*(float)v3.x;
    acc1 += a0*(float)v0.y + a1*(float)v1.y + a2*(float)v2.y + a3*(float)v3.y;
    acc2 += a0*(float)v0.z + a1*(float)v1.z + a2*(float)v2.z + a3*(float)v3.z;
    acc3 += a0*(float)v0.w + a1*(float)v1.w + a2*(float)v2.w + a3*(float)v3.w;
  }
  for (; j < end; j++){
    int s = csr[j];
    float a = alpha[(size_t)j*4 + head];
    half4 v = *(const half4*)(h + (size_t)s*256 + lane*4);
    acc0 += a*(float)v.x; acc1 += a*(float)v.y;
    acc2 += a*(float)v.z; acc3 += a*(float)v.w;
  }

  float o0 = acc0 + bias[lane*4+0];
  float o1 = acc1 + bias[lane*4+1];
  float o2 = acc2 + bias[lane*4+2];
  float o3 = acc3 + bias[lane*4+3];
  o0 = o0 > 0.f ? o0 : __expf(o0) - 1.f;     // ELU
  o1 = o1 > 0.f ? o1 : __expf(o1) - 1.f;
  o2 = o2 > 0.f ? o2 : __expf(o2) - 1.f;
  o3 = o3 > 0.f ? o3 : __expf(o3) - 1.f;
  half4 r; r.x = (f16)o0; r.y = (f16)o1; r.z = (f16)o2; r.w = (f16)o3;
  *(half4*)(out + (size_t)w * 256 + lane * 4) = r;
}

// H=1, C=40 -> out[N,40](fp32) -> d_out
__global__ __launch_bounds__(256) void agg1_k(const f16* __restrict__ h,
                                              const float* __restrict__ alpha,
                                              const int* __restrict__ row_ptr,
                                              const int* __restrict__ csr,
                                              const float* __restrict__ bias,
                                              float* __restrict__ out){
  int w = blockIdx.x * 4 + (threadIdx.x >> 6);
  if (w >= NN) return;
  int lane = threadIdx.x & 63;
  int cl = (lane < 40) ? lane : 0;
  int beg = row_ptr[w], end = row_ptr[w + 1];

  float acc = 0.f;
  int j = beg;
  for (; j + 4 <= end; j += 4){
    int s0 = csr[j], s1 = csr[j+1], s2 = csr[j+2], s3 = csr[j+3];
    float a0 = alpha[j], a1 = alpha[j+1], a2 = alpha[j+2], a3 = alpha[j+3];
    float v0 = (float)h[(size_t)s0*40 + cl];
    float v1 = (float)h[(size_t)s1*40 + cl];
    float v2 = (float)h[(size_t)s2*40 + cl];
    float v3 = (float)h[(size_t)s3*40 + cl];
    acc += a0*v0 + a1*v1 + a2*v2 + a3*v3;
  }
  for (; j < end; j++){
    acc += alpha[j] * (float)h[(size_t)csr[j]*40 + cl];
  }

  if (lane < 40){
    out[(size_t)w * 40 + lane] = acc + bias[lane];
  }
}

// ---------------- driver -----------------------------------------------------------

extern "C" void kernel_launch(void* const* d_in, const int* in_sizes, int n_in,
                              void* d_out, int out_size, void* d_ws, size_t ws_size,
                              hipStream_t stream){
  const float* x   = (const float*)d_in[0];
  const int*   ei  = (const int*)d_in[1];
  const float* W1  = (const float*)d_in[2];
  const float* as1 = (const float*)d_in[3];
  const float* ad1 = (const float*)d_in[4];
  const float* b1  = (const float*)d_in[5];
  const float* W2  = (const float*)d_in[6];
  const float* as2 = (const float*)d_in[7];
  const float* ad2 = (const float*)d_in[8];
  const float* b2  = (const float*)d_in[9];
  const float* W3  = (const float*)d_in[10];
  const float* as3 = (const float*)d_in[11];
  const float* ad3 = (const float*)d_in[12];
  const float* b3  = (const float*)d_in[13];

  const int E = in_sizes[1] / 2;             // 800000
  const int ETOT = E + NN;
  const int* src_arr = ei;
  const int* dst_arr = ei + E;

  char* ws = (char*)d_ws;
  size_t off = 0;
  auto alloc = [&](size_t bytes) -> void* {
    void* p = ws + off; off += (bytes + 255) & ~(size_t)255; return p;
  };
  int*   cnt     = (int*)  alloc((size_t)NN * 4);
  int*   row_ptr = (int*)  alloc((size_t)(NN + 1) * 4);
  int*   cursor  = (int*)  alloc((size_t)NN * 4);
  int*   csr     = (int*)  alloc((size_t)ETOT * 4);
  int*   bsum    = (int*)  alloc((size_t)256 * 4);
  int*   boff    = (int*)  alloc((size_t)256 * 4);
  f16*   W1t     = (f16*)  alloc((size_t)512 * 256 * 2);
  f16*   W2t     = (f16*)  alloc((size_t)256 * 256 * 2);
  f16*   W3t     = (f16*)  alloc((size_t)256 * 40 * 2);
  float* a_s     = (float*)alloc((size_t)NN * 4 * 4);
  float* a_d     = (float*)alloc((size_t)NN * 4 * 4);
  float* alpha   = (float*)alloc((size_t)ETOT * 4 * 4);   // per-edge per-head softmax weight
  f16*   hbuf    = (f16*)  alloc((size_t)NN * 256 * 2);   // fp16 h (per-layer)
  f16*   xbuf    = (f16*)  alloc((size_t)NN * 256 * 2);   // fp16 inter-layer activations
  (void)ws_size; (void)n_in; (void)out_size;

  // CSR build (same graph reused by all 3 layers)
  hipMemsetAsync(cnt, 0, (size_t)NN * 4, stream);
  int egrid = (ETOT + 255) / 256;
  count_k    <<<egrid, 256, 0, stream>>>(dst_arr, cnt, E);
  scan_part_k<<<NB, 256, 0, stream>>>(cnt, bsum);
  scan_top_k <<<1, 256, 0, stream>>>(bsum, boff, row_ptr);
  scan_fin_k <<<NB, 256, 0, stream>>>(cnt, boff, row_ptr, cursor);
  scatter_k  <<<egrid, 256, 0, stream>>>(src_arr, dst_arr, cursor, csr, E);

  // weight transposes (fp32 -> fp16)
  transpose_k<<<(512 * 256 + 255) / 256, 256, 0, stream>>>(W1, W1t, 512, 256);
  transpose_k<<<(256 * 256 + 255) / 256, 256, 0, stream>>>(W2, W2t, 256, 256);
  transpose_k<<<(256 * 40  + 255) / 256, 256, 0, stream>>>(W3, W3t, 256, 40);

  dim3 blk(256);
  dim3 gT((NN + 127) / 128, 2);              // 128x128 tiles, N=256
  dim3 gC((NN + 63) / 64, 1);                // narrow GEMM layer 3 (N=40)
  int nodeblocks = (NN + 3) / 4;             // one wave per node
  int grpblocks  = (NN + 15) / 16;           // 16 nodes per block (16-lane groups)

  // Layer 1: A = x (fp32), K=512
  gemm_tile_k<true> <<<gT, blk, 0, stream>>>(x, W1t, hbuf, NN, 256, 512);
  attn4_k  <<<nodeblocks, blk, 0, stream>>>(hbuf, as1, ad1, a_s, a_d);
  maxden4_k<<<grpblocks, blk, 0, stream>>>(a_s, a_d, row_ptr, csr, alpha);
  agg4_k   <<<nodeblocks, blk, 0, stream>>>(hbuf, alpha, row_ptr, csr, b1, xbuf);

  // Layer 2: A = xbuf (fp16), K=256
  gemm_tile_k<false><<<gT, blk, 0, stream>>>(xbuf, W2t, hbuf, NN, 256, 256);
  attn4_k  <<<nodeblocks, blk, 0, stream>>>(hbuf, as2, ad2, a_s, a_d);
  maxden4_k<<<grpblocks, blk, 0, stream>>>(a_s, a_d, row_ptr, csr, alpha);
  agg4_k   <<<nodeblocks, blk, 0, stream>>>(hbuf, alpha, row_ptr, csr, b2, xbuf);

  // Layer 3 (H=1, C=40) -> d_out (fp32)
  gemm_k<<<gC, blk, 0, stream>>>(xbuf, W3t, hbuf, NN, 40, 256);
  attn1_k  <<<nodeblocks, blk, 0, stream>>>(hbuf, as3, ad3, a_s, a_d);
  maxden1_k<<<grpblocks, blk, 0, stream>>>(a_s, a_d, row_ptr, csr, alpha);
  agg1_k   <<<nodeblocks, blk, 0, stream>>>(hbuf, alpha, row_ptr, csr, b3, (float*)d_out);
}